// Round 9
// baseline (103.892 us; speedup 1.0000x reference)
//
#include <hip/hip_runtime.h>
#include <hip/hip_bf16.h>
#include <math.h>

#define B_ 8
#define H_ 128
#define N_ 64
#define L_ 8192
#define MCH 64                 // chunk length
#define SCH (L_ / MCH)         // 128 chunks per sequence
#define EROW 136               // EBUF row stride (bf16 elems): 272 B, 16B-aligned
#define NSEQ 2                 // sequences per block (same head, b and b+1)

// ---- LDS layout (byte offsets), persistent tables ----
// [0, 34816)       EBUF 128x136 bf16 (per-seq scratch, same-wave rows)
// [34816, 51200)   Q  128x64 bf16 swizzled (persistent)
// [51200, 67584)   P  64x128 bf16 swizzled (persistent)
// [67584, 75776)   seg[2][2][8][64] f32 (double-buffered per seq, 8 segments)
// [75776, 76032)   kv[64] f32
// total 76032 B -> 2 blocks/CU (160 KiB LDS)
#define LDS_Q     34816
#define LDS_P     51200
#define LDS_SEG   67584
#define LDS_KV    75776
#define LDS_TOTAL 76032

typedef __attribute__((ext_vector_type(8))) short bf16x8;  // MFMA A/B frag
typedef __attribute__((ext_vector_type(4))) float f32x4;   // MFMA C/D frag / NT vec

__device__ __forceinline__ float bf2f(ushort s) { return __uint_as_float(((uint)s) << 16); }
__device__ __forceinline__ uint packbf2(float a, float b) {
    __hip_bfloat162 h = __float22bfloat162_rn(make_float2(a, b));
    union { __hip_bfloat162 h2; uint u; } cv; cv.h2 = h;
    return cv.u;
}
__device__ __forceinline__ bf16x8 pack_bf8(f32x4 a, f32x4 b) {
    union { uint u[4]; bf16x8 v; } r;
    r.u[0] = packbf2(a[0], a[1]); r.u[1] = packbf2(a[2], a[3]);
    r.u[2] = packbf2(b[0], b[1]); r.u[3] = packbf2(b[2], b[3]);
    return r.v;
}

// ============ fused kernel, 2 sequences per block ============
// Tables built once per block; Q and P persist in LDS. EBUF rows [32g,32g+32)
// are written/scanned/consumed by the SAME wave g in both seqs -> no barriers
// on EBUF edges. Memory-stream smoothing: (1) odd blocks build tables before
// issuing x0 loads (halves the t=0 device-wide read burst); (2) seq1's loads
// are issued in two halves spread through seq0's compute.
__global__ __launch_bounds__(256, 2) void s4d_fused(
    const float* __restrict__ x,
    const float* __restrict__ A_re, const float* __restrict__ A_im,
    const float* __restrict__ Cp, const float* __restrict__ Dp,
    const float* __restrict__ log_delta,
    float* __restrict__ out)
{
    __shared__ __align__(16) char lds[LDS_TOTAL];
    ushort* EBUF = (ushort*)lds;
    char*   QTBL = lds + LDS_Q;
    char*   PTBL = lds + LDS_P;
    float*  seg  = (float*)(lds + LDS_SEG);   // [sb][r/i][8][64]
    float*  kv   = (float*)(lds + LDS_KV);

    const int h   = blockIdx.x % H_;
    const int bp  = blockIdx.x / H_;          // 0..3 -> b = 2bp, 2bp+1
    const int tid = threadIdx.x;
    const int w   = tid >> 6;
    const int lane = tid & 63;
    const int n16 = lane & 15, q = lane >> 4;
    const int n = lane, g = w;

    // ---- per-mode parameters (once per block) ----
    float are = fminf(A_re[h * N_ + n], -1e-4f);
    float aim = A_im[h * N_ + n];
    float step = expf(log_delta[h]);
    float dre = step * are, dim = step * aim;
    float er = expf(dre);
    float sd, cd; sincosf(dim, &sd, &cd);
    float rre = er * cd, rim = er * sd;
    float cre = Cp[(h * N_ + n) * 2 + 0];
    float cim = Cp[(h * N_ + n) * 2 + 1];
    float inv  = 1.0f / (are * are + aim * aim);
    float numr = rre - 1.0f, numi = rim;
    float consr = (numr * are + numi * aim) * inv;
    float consi = (numi * are - numr * aim) * inv;
    float wr = cre * consr - cim * consi;
    float wi = cre * consi + cim * consr;
    float dval = Dp[h];
    // precise r^64 (6 squarings); segment multiplier m16 = r^1024 later
    float m64r = rre, m64i = rim;
#pragma unroll
    for (int k = 0; k < 6; ++k) { float tr = m64r*m64r - m64i*m64i, ti = 2.f*m64r*m64i; m64r = tr; m64i = ti; }
    const float mr = m64r, mi = m64i;

    auto rp = [&](float d, float& pr, float& pi) {
        float ex = __expf(d * dre);
        float ang = d * dim;
        float s = __sinf(ang), c2 = __cosf(ang);
        pr = ex * c2; pi = ex * s;
    };

    // ---- seq pointers ----
    const float* xs0 = x   + ((size_t)(2 * bp) * H_ + h) * L_;
    const float* xs1 = xs0 + (size_t)H_ * L_;
    float* op0 = out + ((size_t)(2 * bp) * H_ + h) * L_;
    float* op1 = op0 + (size_t)H_ * L_;

    bf16x8 xb0[2][2];
    f32x4 raw1[2][2][2];

    auto loadX0 = [&]() {
#pragma unroll
        for (int ic = 0; ic < 2; ++ic) {
            int c = (2 * w + ic) * 16 + n16;
#pragma unroll
            for (int kc = 0; kc < 2; ++kc) {
                const float* p0 = xs0 + c * MCH + kc * 32 + q * 8;
                f32x4 f0 = __builtin_nontemporal_load((const f32x4*)p0);
                f32x4 f1 = __builtin_nontemporal_load((const f32x4*)p0 + 1);
                xb0[ic][kc] = pack_bf8(f0, f1);
            }
        }
    };

    auto buildQ = [&]() {
        uint qr[8], qi[8];
#pragma unroll
        for (int i = 0; i < 8; ++i) {
            int t0 = g * 16 + 2 * i;
            float ar0, ai0, ar1, ai1;
            rp((float)(63 - t0), ar0, ai0);
            rp((float)(62 - t0), ar1, ai1);
            qr[i] = packbf2(ar0, ar1);
            qi[i] = packbf2(ai0, ai1);
        }
        const int ra = 2 * n, rb = 2 * n + 1;
        const uint xa = (uint)(ra & 7) << 4, xbm = (uint)(rb & 7) << 4;
        *(uint4*)(QTBL + ((ra * 128 + g * 32     ) ^ xa))  = ((uint4*)qr)[0];
        *(uint4*)(QTBL + ((ra * 128 + g * 32 + 16) ^ xa))  = ((uint4*)qr)[1];
        *(uint4*)(QTBL + ((rb * 128 + g * 32     ) ^ xbm)) = ((uint4*)qi)[0];
        *(uint4*)(QTBL + ((rb * 128 + g * 32 + 16) ^ xbm)) = ((uint4*)qi)[1];
    };

    auto buildKV = [&]() {
        float kvloc[16];
#pragma unroll
        for (int j = 0; j < 16; ++j) {
            float pr, pi; rp((float)(g * 16 + j), pr, pi);
            kvloc[j] = wr * pr - wi * pi;
        }
#pragma unroll
        for (int j = 0; j < 16; ++j) {
#pragma unroll
            for (int s = 1; s < 64; s <<= 1)
                kvloc[j] += __shfl_xor(kvloc[j], s, 64);
        }
#pragma unroll
        for (int j = 0; j < 16; ++j)
            if (n == j) kv[g * 16 + j] = kvloc[j];
    };

    // ---- parity-staggered prologue: halves the t=0 read burst ----
    if ((blockIdx.x & 1) == 0) {
        loadX0(); buildQ(); buildKV();
    } else {
        buildQ(); buildKV(); loadX0();
    }
    __syncthreads();                                     // B1: Q, kv ready

    // ---- m16 = r^1024 (4 squarings from r^64): segment-prefix multiplier ----
    float m16r = mr, m16i = mi;
#pragma unroll
    for (int k = 0; k < 4; ++k) { float tr = m16r*m16r - m16i*m16i, ti = 2.f*m16r*m16i; m16r = tr; m16i = ti; }

    // ---- T A-frags from kv (once per block) ----
    bf16x8 tf[4][2];
#pragma unroll
    for (int rt = 0; rt < 4; ++rt) {
        int row = rt * 16 + n16;
        union { uint u[4]; bf16x8 v; } f0, f1;
#pragma unroll
        for (int kc = 0; kc < 2; ++kc) {
#pragma unroll
            for (int ki = 0; ki < 4; ++ki) {
                int t0 = kc * 32 + q * 8 + 2 * ki;
                int i0 = row - t0, i1 = i0 - 1;
                float v0 = kv[i0 & 63]; v0 = (i0 >= 0) ? v0 : 0.f; if (i0 == 0) v0 += dval;
                float v1 = kv[i1 & 63]; v1 = (i1 >= 0) ? v1 : 0.f; if (i1 == 0) v1 += dval;
                if (kc == 0) f0.u[ki] = packbf2(v0, v1); else f1.u[ki] = packbf2(v0, v1);
            }
        }
        tf[rt][0] = f0.v; tf[rt][1] = f1.v;
    }

    const uint xr = (uint)(n16 & 7) << 4;

    // ================= per-sequence processing =================
    auto do_seq = [&](const bf16x8 (&xb)[2][2], int sb, float* op,
                      bool buildP, bool issueRaw1) {
        // ---- Phase A: E = Q * X -> EBUF rows [32w,32w+32) (own wave) ----
#pragma unroll
        for (int rt = 0; rt < 8; ++rt) {
            int row = rt * 16 + n16;
            bf16x8 a0 = *(const bf16x8*)(QTBL + ((row * 128      + q * 16) ^ xr));
            bf16x8 a1 = *(const bf16x8*)(QTBL + ((row * 128 + 64 + q * 16) ^ xr));
#pragma unroll
            for (int ic = 0; ic < 2; ++ic) {
                f32x4 acc = {0.f, 0.f, 0.f, 0.f};
                acc = __builtin_amdgcn_mfma_f32_16x16x32_bf16(a0, xb[ic][0], acc, 0, 0, 0);
                acc = __builtin_amdgcn_mfma_f32_16x16x32_bf16(a1, xb[ic][1], acc, 0, 0, 0);
                int c = (2 * w + ic) * 16 + n16;
                uint2 st = make_uint2(packbf2(acc[0], acc[1]), packbf2(acc[2], acc[3]));
                *(uint2*)&EBUF[c * EROW + rt * 16 + q * 4] = st;
            }
        }

        // ---- seq1 loads, first half (kc=0): de-phased read stream ----
        if (issueRaw1) {
#pragma unroll
            for (int ic = 0; ic < 2; ++ic) {
                int c = (2 * w + ic) * 16 + n16;
                const float* p1 = xs1 + c * MCH + q * 8;
                raw1[ic][0][0] = __builtin_nontemporal_load((const f32x4*)p1);
                raw1[ic][0][1] = __builtin_nontemporal_load((const f32x4*)p1 + 1);
            }
        }

        // ---- pass 1: two interleaved 16-chains (same-wave EBUF) ----
        float* sr_ = seg + sb * 1024;         // [r][8][64]
        float* si_ = sr_ + 512;
        {
            float sAr = 0.f, sAi = 0.f, sBr = 0.f, sBi = 0.f;
#pragma unroll
            for (int j = 0; j < 16; ++j) {
                uint eA = *(const uint*)&EBUF[(g * 32 + j     ) * EROW + 2 * n];
                uint eB = *(const uint*)&EBUF[(g * 32 + 16 + j) * EROW + 2 * n];
                float eAr = bf2f((ushort)(eA & 0xffffu)), eAi = bf2f((ushort)(eA >> 16));
                float eBr = bf2f((ushort)(eB & 0xffffu)), eBi = bf2f((ushort)(eB >> 16));
                float nAr = eAr + mr * sAr - mi * sAi;
                float nAi = eAi + mr * sAi + mi * sAr;
                float nBr = eBr + mr * sBr - mi * sBi;
                float nBi = eBi + mr * sBi + mi * sBr;
                sAr = nAr; sAi = nAi; sBr = nBr; sBi = nBi;
            }
            sr_[(2 * g    ) * 64 + n] = sAr; si_[(2 * g    ) * 64 + n] = sAi;
            sr_[(2 * g + 1) * 64 + n] = sBr; si_[(2 * g + 1) * 64 + n] = sBi;
        }

        // ---- T*X (overlaps pass1's dependent chain) ----
        f32x4 accT[4][2];
#pragma unroll
        for (int rt = 0; rt < 4; ++rt) {
#pragma unroll
            for (int ic = 0; ic < 2; ++ic) {
                f32x4 a = {0.f, 0.f, 0.f, 0.f};
                a = __builtin_amdgcn_mfma_f32_16x16x32_bf16(tf[rt][0], xb[ic][0], a, 0, 0, 0);
                a = __builtin_amdgcn_mfma_f32_16x16x32_bf16(tf[rt][1], xb[ic][1], a, 0, 0, 0);
                accT[rt][ic] = a;
            }
        }

        // ---- seq1 loads, second half (kc=1) ----
        if (issueRaw1) {
#pragma unroll
            for (int ic = 0; ic < 2; ++ic) {
                int c = (2 * w + ic) * 16 + n16;
                const float* p1 = xs1 + c * MCH + 32 + q * 8;
                raw1[ic][1][0] = __builtin_nontemporal_load((const f32x4*)p1);
                raw1[ic][1][1] = __builtin_nontemporal_load((const f32x4*)p1 + 1);
            }
        }

        // ---- P build (seq0 only; ordered before Phase C by the barrier) ----
        if (buildP) {
#pragma unroll
            for (int i = 0; i < 16; ++i) {
                int j = g * 16 + i;
                float pr, pi; rp((float)(j + 1), pr, pi);
                float ur = wr * pr - wi * pi;
                float ui = wr * pi + wi * pr;
                *(uint*)(PTBL + ((j * 256 + n * 4) ^ ((uint)(j & 7) << 4))) = packbf2(ur, -ui);
            }
        }
        __syncthreads();                                 // seg[sb] (+P) ready

        // ---- exclusive seg prefix (<=7 terms) + pass 2 (2 chains) ----
        {
            float pr2 = 0.f, pi2 = 0.f;
            for (int s = 0; s < 2 * g; ++s) {
                float Er = sr_[s * 64 + n], Ei = si_[s * 64 + n];
                float nr = Er + m16r * pr2 - m16i * pi2;
                float ni = Ei + m16r * pi2 + m16i * pr2;
                pr2 = nr; pi2 = ni;
            }
            float sAr = pr2, sAi = pi2;
            float Gr = sr_[(2 * g) * 64 + n], Gi = si_[(2 * g) * 64 + n];
            float sBr = Gr + m16r * pr2 - m16i * pi2;
            float sBi = Gi + m16r * pi2 + m16i * pr2;
#pragma unroll
            for (int j = 0; j < 16; ++j) {
                uint* epA = (uint*)&EBUF[(g * 32 + j     ) * EROW + 2 * n];
                uint* epB = (uint*)&EBUF[(g * 32 + 16 + j) * EROW + 2 * n];
                uint eA = *epA, eB = *epB;
                float eAr = bf2f((ushort)(eA & 0xffffu)), eAi = bf2f((ushort)(eA >> 16));
                float eBr = bf2f((ushort)(eB & 0xffffu)), eBi = bf2f((ushort)(eB >> 16));
                *epA = packbf2(sAr, sAi);
                *epB = packbf2(sBr, sBi);
                float nAr = eAr + mr * sAr - mi * sAi;
                float nAi = eAi + mr * sAi + mi * sAr;
                float nBr = eBr + mr * sBr - mi * sBi;
                float nBi = eBi + mr * sBi + mi * sBr;
                sAr = nAr; sAi = nAi; sBr = nBr; sBi = nBi;
            }
        }

        // ---- Phase C: OUT = accT + P*SV (own-wave EBUF rows) ----
#pragma unroll
        for (int rt = 0; rt < 4; ++rt) {
            int row = rt * 16 + n16;
            bf16x8 p0 = *(const bf16x8*)(PTBL + ((row * 256       + q * 16) ^ xr));
            bf16x8 p1 = *(const bf16x8*)(PTBL + ((row * 256 +  64 + q * 16) ^ xr));
            bf16x8 p2 = *(const bf16x8*)(PTBL + ((row * 256 + 128 + q * 16) ^ xr));
            bf16x8 p3 = *(const bf16x8*)(PTBL + ((row * 256 + 192 + q * 16) ^ xr));
#pragma unroll
            for (int ic = 0; ic < 2; ++ic) {
                int c = (2 * w + ic) * 16 + n16;
                f32x4 accP = {0.f, 0.f, 0.f, 0.f};
                accP = __builtin_amdgcn_mfma_f32_16x16x32_bf16(p0,
                           *(const bf16x8*)&EBUF[c * EROW +       q * 8], accP, 0, 0, 0);
                accP = __builtin_amdgcn_mfma_f32_16x16x32_bf16(p1,
                           *(const bf16x8*)&EBUF[c * EROW +  32 + q * 8], accP, 0, 0, 0);
                accP = __builtin_amdgcn_mfma_f32_16x16x32_bf16(p2,
                           *(const bf16x8*)&EBUF[c * EROW +  64 + q * 8], accP, 0, 0, 0);
                accP = __builtin_amdgcn_mfma_f32_16x16x32_bf16(p3,
                           *(const bf16x8*)&EBUF[c * EROW +  96 + q * 8], accP, 0, 0, 0);
                f32x4 o;
                o[0] = accT[rt][ic][0] + accP[0];
                o[1] = accT[rt][ic][1] + accP[1];
                o[2] = accT[rt][ic][2] + accP[2];
                o[3] = accT[rt][ic][3] + accP[3];
                __builtin_nontemporal_store(o, (f32x4*)(op + c * MCH + rt * 16 + q * 4));
            }
        }
    };

    do_seq(xb0, 0, op0, true, true);

    // pack seq1 (loads issued during seq0; latency covered by seq0 compute)
    bf16x8 xb1[2][2];
#pragma unroll
    for (int ic = 0; ic < 2; ++ic)
#pragma unroll
        for (int kc = 0; kc < 2; ++kc)
            xb1[ic][kc] = pack_bf8(raw1[ic][kc][0], raw1[ic][kc][1]);

    do_seq(xb1, 1, op1, false, false);
}

extern "C" void kernel_launch(void* const* d_in, const int* in_sizes, int n_in,
                              void* d_out, int out_size, void* d_ws, size_t ws_size,
                              hipStream_t stream)
{
    const float* x  = (const float*)d_in[0];
    const float* Ar = (const float*)d_in[1];
    const float* Ai = (const float*)d_in[2];
    const float* C  = (const float*)d_in[3];
    const float* D  = (const float*)d_in[4];
    const float* ld = (const float*)d_in[5];
    float* out = (float*)d_out;
    (void)d_ws; (void)ws_size;               // workspace unused: tables live in LDS

    hipLaunchKernelGGL(s4d_fused, dim3(B_ * H_ / NSEQ), dim3(256), 0, stream,
                       x, Ar, Ai, C, D, ld, out);
}

// Round 10
// 101.520 us; speedup vs baseline: 1.0234x; 1.0234x over previous
//
#include <hip/hip_runtime.h>
#include <hip/hip_bf16.h>
#include <math.h>

#define B_ 8
#define H_ 128
#define N_ 64
#define L_ 8192
#define MCH 64                 // chunk length
#define SCH (L_ / MCH)         // 128 chunks per sequence
#define EROW 136               // EBUF row stride (bf16 elems): 272 B, 16B-aligned
#define NSEQ 2                 // sequences per block (same head, b and b+1)

// ---- LDS layout (byte offsets), persistent tables ----
// [0, 34816)       EBUF 128x136 bf16 (per-seq scratch, same-wave rows)
// [34816, 51200)   Q  128x64 bf16 swizzled (persistent)
// [51200, 67584)   P  64x128 bf16 swizzled (persistent)
// [67584, 75776)   seg[2][2][8][64] f32 (double-buffered per seq, 8 segments)
// [75776, 76032)   kv[64] f32
// total 76032 B -> 2 blocks/CU (160 KiB LDS)
#define LDS_Q     34816
#define LDS_P     51200
#define LDS_SEG   67584
#define LDS_KV    75776
#define LDS_TOTAL 76032

typedef __attribute__((ext_vector_type(8))) short bf16x8;  // MFMA A/B frag
typedef __attribute__((ext_vector_type(4))) float f32x4;   // MFMA C/D frag / NT vec

__device__ __forceinline__ float bf2f(ushort s) { return __uint_as_float(((uint)s) << 16); }
__device__ __forceinline__ uint packbf2(float a, float b) {
    __hip_bfloat162 h = __float22bfloat162_rn(make_float2(a, b));
    union { __hip_bfloat162 h2; uint u; } cv; cv.h2 = h;
    return cv.u;
}
__device__ __forceinline__ bf16x8 pack_bf8(f32x4 a, f32x4 b) {
    union { uint u[4]; bf16x8 v; } r;
    r.u[0] = packbf2(a[0], a[1]); r.u[1] = packbf2(a[2], a[3]);
    r.u[2] = packbf2(b[0], b[1]); r.u[3] = packbf2(b[2], b[3]);
    return r.v;
}

// ============ fused kernel, 2 sequences per block ============
// Tables built once per block; Q and P persist in LDS. EBUF rows [32g,32g+32)
// are written/scanned/consumed by the SAME wave g in both seqs -> no barriers
// on EBUF edges. seq1's x-loads are issued AFTER seq0's Phase A so the
// device-wide read stream overlaps seq0's compute and store stream
// (de-phased memory pipeline instead of phase-locked bursts).
__global__ __launch_bounds__(256, 2) void s4d_fused(
    const float* __restrict__ x,
    const float* __restrict__ A_re, const float* __restrict__ A_im,
    const float* __restrict__ Cp, const float* __restrict__ Dp,
    const float* __restrict__ log_delta,
    float* __restrict__ out)
{
    __shared__ __align__(16) char lds[LDS_TOTAL];
    ushort* EBUF = (ushort*)lds;
    char*   QTBL = lds + LDS_Q;
    char*   PTBL = lds + LDS_P;
    float*  seg  = (float*)(lds + LDS_SEG);   // [sb][r/i][8][64]
    float*  kv   = (float*)(lds + LDS_KV);

    const int h   = blockIdx.x % H_;
    const int bp  = blockIdx.x / H_;          // 0..3 -> b = 2bp, 2bp+1
    const int tid = threadIdx.x;
    const int w   = tid >> 6;
    const int lane = tid & 63;
    const int n16 = lane & 15, q = lane >> 4;
    const int n = lane, g = w;

    // ---- per-mode parameters (once per block) ----
    float are = fminf(A_re[h * N_ + n], -1e-4f);
    float aim = A_im[h * N_ + n];
    float step = expf(log_delta[h]);
    float dre = step * are, dim = step * aim;
    float er = expf(dre);
    float sd, cd; sincosf(dim, &sd, &cd);
    float rre = er * cd, rim = er * sd;
    float cre = Cp[(h * N_ + n) * 2 + 0];
    float cim = Cp[(h * N_ + n) * 2 + 1];
    float inv  = 1.0f / (are * are + aim * aim);
    float numr = rre - 1.0f, numi = rim;
    float consr = (numr * are + numi * aim) * inv;
    float consi = (numi * are - numr * aim) * inv;
    float wr = cre * consr - cim * consi;
    float wi = cre * consi + cim * consr;
    float dval = Dp[h];
    // precise r^64 (6 squarings); segment multiplier m16 = r^1024 later
    float m64r = rre, m64i = rim;
#pragma unroll
    for (int k = 0; k < 6; ++k) { float tr = m64r*m64r - m64i*m64i, ti = 2.f*m64r*m64i; m64r = tr; m64i = ti; }
    const float mr = m64r, mi = m64i;

    auto rp = [&](float d, float& pr, float& pi) {
        float ex = __expf(d * dre);
        float ang = d * dim;
        float s = __sinf(ang), c2 = __cosf(ang);
        pr = ex * c2; pi = ex * s;
    };

    // ---- seq pointers ----
    const float* xs0 = x   + ((size_t)(2 * bp) * H_ + h) * L_;
    const float* xs1 = xs0 + (size_t)H_ * L_;
    float* op0 = out + ((size_t)(2 * bp) * H_ + h) * L_;
    float* op1 = op0 + (size_t)H_ * L_;

    // ---- seq0 x load+pack only (seq1 loads issued after seq0 Phase A) ----
    bf16x8 xb0[2][2];
    f32x4 raw1[2][2][2];
#pragma unroll
    for (int ic = 0; ic < 2; ++ic) {
        int c = (2 * w + ic) * 16 + n16;
#pragma unroll
        for (int kc = 0; kc < 2; ++kc) {
            const float* p0 = xs0 + c * MCH + kc * 32 + q * 8;
            f32x4 f0 = __builtin_nontemporal_load((const f32x4*)p0);
            f32x4 f1 = __builtin_nontemporal_load((const f32x4*)p0 + 1);
            xb0[ic][kc] = pack_bf8(f0, f1);
        }
    }

    // ---- Q build: rows 2n,2n+1, cols [16g,+16), swizzled ----
    {
        uint qr[8], qi[8];
#pragma unroll
        for (int i = 0; i < 8; ++i) {
            int t0 = g * 16 + 2 * i;
            float ar0, ai0, ar1, ai1;
            rp((float)(63 - t0), ar0, ai0);
            rp((float)(62 - t0), ar1, ai1);
            qr[i] = packbf2(ar0, ar1);
            qi[i] = packbf2(ai0, ai1);
        }
        const int ra = 2 * n, rb = 2 * n + 1;
        const uint xa = (uint)(ra & 7) << 4, xbm = (uint)(rb & 7) << 4;
        *(uint4*)(QTBL + ((ra * 128 + g * 32     ) ^ xa))  = ((uint4*)qr)[0];
        *(uint4*)(QTBL + ((ra * 128 + g * 32 + 16) ^ xa))  = ((uint4*)qr)[1];
        *(uint4*)(QTBL + ((rb * 128 + g * 32     ) ^ xbm)) = ((uint4*)qi)[0];
        *(uint4*)(QTBL + ((rb * 128 + g * 32 + 16) ^ xbm)) = ((uint4*)qi)[1];
    }

    // ---- kv[d] = Re(sum_n w r^d): 64-lane butterfly ----
    {
        float kvloc[16];
#pragma unroll
        for (int j = 0; j < 16; ++j) {
            float pr, pi; rp((float)(g * 16 + j), pr, pi);
            kvloc[j] = wr * pr - wi * pi;
        }
#pragma unroll
        for (int j = 0; j < 16; ++j) {
#pragma unroll
            for (int s = 1; s < 64; s <<= 1)
                kvloc[j] += __shfl_xor(kvloc[j], s, 64);
        }
#pragma unroll
        for (int j = 0; j < 16; ++j)
            if (n == j) kv[g * 16 + j] = kvloc[j];
    }
    __syncthreads();                                     // B1: Q, kv ready

    // ---- m16 = r^1024 (4 squarings from r^64): segment-prefix multiplier ----
    float m16r = mr, m16i = mi;
#pragma unroll
    for (int k = 0; k < 4; ++k) { float tr = m16r*m16r - m16i*m16i, ti = 2.f*m16r*m16i; m16r = tr; m16i = ti; }

    // ---- T A-frags from kv (once per block) ----
    bf16x8 tf[4][2];
#pragma unroll
    for (int rt = 0; rt < 4; ++rt) {
        int row = rt * 16 + n16;
        union { uint u[4]; bf16x8 v; } f0, f1;
#pragma unroll
        for (int kc = 0; kc < 2; ++kc) {
#pragma unroll
            for (int ki = 0; ki < 4; ++ki) {
                int t0 = kc * 32 + q * 8 + 2 * ki;
                int i0 = row - t0, i1 = i0 - 1;
                float v0 = kv[i0 & 63]; v0 = (i0 >= 0) ? v0 : 0.f; if (i0 == 0) v0 += dval;
                float v1 = kv[i1 & 63]; v1 = (i1 >= 0) ? v1 : 0.f; if (i1 == 0) v1 += dval;
                if (kc == 0) f0.u[ki] = packbf2(v0, v1); else f1.u[ki] = packbf2(v0, v1);
            }
        }
        tf[rt][0] = f0.v; tf[rt][1] = f1.v;
    }

    const uint xr = (uint)(n16 & 7) << 4;

    // ================= per-sequence processing =================
    auto do_seq = [&](const bf16x8 (&xb)[2][2], int sb, float* op,
                      bool buildP, bool issueRaw1) {
        // ---- Phase A: E = Q * X -> EBUF rows [32w,32w+32) (own wave) ----
#pragma unroll
        for (int rt = 0; rt < 8; ++rt) {
            int row = rt * 16 + n16;
            bf16x8 a0 = *(const bf16x8*)(QTBL + ((row * 128      + q * 16) ^ xr));
            bf16x8 a1 = *(const bf16x8*)(QTBL + ((row * 128 + 64 + q * 16) ^ xr));
#pragma unroll
            for (int ic = 0; ic < 2; ++ic) {
                f32x4 acc = {0.f, 0.f, 0.f, 0.f};
                acc = __builtin_amdgcn_mfma_f32_16x16x32_bf16(a0, xb[ic][0], acc, 0, 0, 0);
                acc = __builtin_amdgcn_mfma_f32_16x16x32_bf16(a1, xb[ic][1], acc, 0, 0, 0);
                int c = (2 * w + ic) * 16 + n16;
                uint2 st = make_uint2(packbf2(acc[0], acc[1]), packbf2(acc[2], acc[3]));
                *(uint2*)&EBUF[c * EROW + rt * 16 + q * 4] = st;
            }
        }

        // ---- issue seq1 raw loads NOW (seq0 pass only): their HBM latency
        //      hides under the rest of seq0's compute; device-wide, reads
        //      de-phase from the t=0 burst and overlap stores ----
        if (issueRaw1) {
#pragma unroll
            for (int ic = 0; ic < 2; ++ic) {
                int c = (2 * w + ic) * 16 + n16;
#pragma unroll
                for (int kc = 0; kc < 2; ++kc) {
                    const float* p1 = xs1 + c * MCH + kc * 32 + q * 8;
                    raw1[ic][kc][0] = __builtin_nontemporal_load((const f32x4*)p1);
                    raw1[ic][kc][1] = __builtin_nontemporal_load((const f32x4*)p1 + 1);
                }
            }
        }

        // ---- pass 1: two interleaved 16-chains (same-wave EBUF) ----
        float* sr_ = seg + sb * 1024;         // [r][8][64]
        float* si_ = sr_ + 512;
        {
            float sAr = 0.f, sAi = 0.f, sBr = 0.f, sBi = 0.f;
#pragma unroll
            for (int j = 0; j < 16; ++j) {
                uint eA = *(const uint*)&EBUF[(g * 32 + j     ) * EROW + 2 * n];
                uint eB = *(const uint*)&EBUF[(g * 32 + 16 + j) * EROW + 2 * n];
                float eAr = bf2f((ushort)(eA & 0xffffu)), eAi = bf2f((ushort)(eA >> 16));
                float eBr = bf2f((ushort)(eB & 0xffffu)), eBi = bf2f((ushort)(eB >> 16));
                float nAr = eAr + mr * sAr - mi * sAi;
                float nAi = eAi + mr * sAi + mi * sAr;
                float nBr = eBr + mr * sBr - mi * sBi;
                float nBi = eBi + mr * sBi + mi * sBr;
                sAr = nAr; sAi = nAi; sBr = nBr; sBi = nBi;
            }
            sr_[(2 * g    ) * 64 + n] = sAr; si_[(2 * g    ) * 64 + n] = sAi;
            sr_[(2 * g + 1) * 64 + n] = sBr; si_[(2 * g + 1) * 64 + n] = sBi;
        }

        // ---- T*X (overlaps pass1's dependent chain) ----
        f32x4 accT[4][2];
#pragma unroll
        for (int rt = 0; rt < 4; ++rt) {
#pragma unroll
            for (int ic = 0; ic < 2; ++ic) {
                f32x4 a = {0.f, 0.f, 0.f, 0.f};
                a = __builtin_amdgcn_mfma_f32_16x16x32_bf16(tf[rt][0], xb[ic][0], a, 0, 0, 0);
                a = __builtin_amdgcn_mfma_f32_16x16x32_bf16(tf[rt][1], xb[ic][1], a, 0, 0, 0);
                accT[rt][ic] = a;
            }
        }

        // ---- P build (seq0 only; ordered before Phase C by the barrier) ----
        if (buildP) {
#pragma unroll
            for (int i = 0; i < 16; ++i) {
                int j = g * 16 + i;
                float pr, pi; rp((float)(j + 1), pr, pi);
                float ur = wr * pr - wi * pi;
                float ui = wr * pi + wi * pr;
                *(uint*)(PTBL + ((j * 256 + n * 4) ^ ((uint)(j & 7) << 4))) = packbf2(ur, -ui);
            }
        }
        __syncthreads();                                 // seg[sb] (+P) ready

        // ---- exclusive seg prefix (<=7 terms) + pass 2 (2 chains) ----
        {
            float pr2 = 0.f, pi2 = 0.f;
            for (int s = 0; s < 2 * g; ++s) {
                float Er = sr_[s * 64 + n], Ei = si_[s * 64 + n];
                float nr = Er + m16r * pr2 - m16i * pi2;
                float ni = Ei + m16r * pi2 + m16i * pr2;
                pr2 = nr; pi2 = ni;
            }
            float sAr = pr2, sAi = pi2;
            float Gr = sr_[(2 * g) * 64 + n], Gi = si_[(2 * g) * 64 + n];
            float sBr = Gr + m16r * pr2 - m16i * pi2;
            float sBi = Gi + m16r * pi2 + m16i * pr2;
#pragma unroll
            for (int j = 0; j < 16; ++j) {
                uint* epA = (uint*)&EBUF[(g * 32 + j     ) * EROW + 2 * n];
                uint* epB = (uint*)&EBUF[(g * 32 + 16 + j) * EROW + 2 * n];
                uint eA = *epA, eB = *epB;
                float eAr = bf2f((ushort)(eA & 0xffffu)), eAi = bf2f((ushort)(eA >> 16));
                float eBr = bf2f((ushort)(eB & 0xffffu)), eBi = bf2f((ushort)(eB >> 16));
                *epA = packbf2(sAr, sAi);
                *epB = packbf2(sBr, sBi);
                float nAr = eAr + mr * sAr - mi * sAi;
                float nAi = eAi + mr * sAi + mi * sAr;
                float nBr = eBr + mr * sBr - mi * sBi;
                float nBi = eBi + mr * sBi + mi * sBr;
                sAr = nAr; sAi = nAi; sBr = nBr; sBi = nBi;
            }
        }

        // ---- Phase C: OUT = accT + P*SV (own-wave EBUF rows) ----
#pragma unroll
        for (int rt = 0; rt < 4; ++rt) {
            int row = rt * 16 + n16;
            bf16x8 p0 = *(const bf16x8*)(PTBL + ((row * 256       + q * 16) ^ xr));
            bf16x8 p1 = *(const bf16x8*)(PTBL + ((row * 256 +  64 + q * 16) ^ xr));
            bf16x8 p2 = *(const bf16x8*)(PTBL + ((row * 256 + 128 + q * 16) ^ xr));
            bf16x8 p3 = *(const bf16x8*)(PTBL + ((row * 256 + 192 + q * 16) ^ xr));
#pragma unroll
            for (int ic = 0; ic < 2; ++ic) {
                int c = (2 * w + ic) * 16 + n16;
                f32x4 accP = {0.f, 0.f, 0.f, 0.f};
                accP = __builtin_amdgcn_mfma_f32_16x16x32_bf16(p0,
                           *(const bf16x8*)&EBUF[c * EROW +       q * 8], accP, 0, 0, 0);
                accP = __builtin_amdgcn_mfma_f32_16x16x32_bf16(p1,
                           *(const bf16x8*)&EBUF[c * EROW +  32 + q * 8], accP, 0, 0, 0);
                accP = __builtin_amdgcn_mfma_f32_16x16x32_bf16(p2,
                           *(const bf16x8*)&EBUF[c * EROW +  64 + q * 8], accP, 0, 0, 0);
                accP = __builtin_amdgcn_mfma_f32_16x16x32_bf16(p3,
                           *(const bf16x8*)&EBUF[c * EROW +  96 + q * 8], accP, 0, 0, 0);
                f32x4 o;
                o[0] = accT[rt][ic][0] + accP[0];
                o[1] = accT[rt][ic][1] + accP[1];
                o[2] = accT[rt][ic][2] + accP[2];
                o[3] = accT[rt][ic][3] + accP[3];
                __builtin_nontemporal_store(o, (f32x4*)(op + c * MCH + rt * 16 + q * 4));
            }
        }
    };

    do_seq(xb0, 0, op0, true, true);

    // pack seq1 (loads issued during seq0; latency covered by seq0 compute)
    bf16x8 xb1[2][2];
#pragma unroll
    for (int ic = 0; ic < 2; ++ic)
#pragma unroll
        for (int kc = 0; kc < 2; ++kc)
            xb1[ic][kc] = pack_bf8(raw1[ic][kc][0], raw1[ic][kc][1]);

    do_seq(xb1, 1, op1, false, false);
}

extern "C" void kernel_launch(void* const* d_in, const int* in_sizes, int n_in,
                              void* d_out, int out_size, void* d_ws, size_t ws_size,
                              hipStream_t stream)
{
    const float* x  = (const float*)d_in[0];
    const float* Ar = (const float*)d_in[1];
    const float* Ai = (const float*)d_in[2];
    const float* C  = (const float*)d_in[3];
    const float* D  = (const float*)d_in[4];
    const float* ld = (const float*)d_in[5];
    float* out = (float*)d_out;
    (void)d_ws; (void)ws_size;               // workspace unused: tables live in LDS

    hipLaunchKernelGGL(s4d_fused, dim3(B_ * H_ / NSEQ), dim3(256), 0, stream,
                       x, Ar, Ai, C, D, ld, out);
}